// Round 9
// baseline (285.705 us; speedup 1.0000x reference)
//
#include <hip/hip_runtime.h>
#include <math.h>

// ---------------------------------------------------------------------------
// SingleHeadSelfAttention: B=4, S=2048, C=2048, d=512
// R15: 128x128 / 4-wave / 3-slot-ring core (R14 geometry) with a ONE-CHUNK
//      REGISTER LOOKAHEAD: fragments for chunk j+1 are ds_read-ISSUED before
//      chunk j's MFMA cluster (double reg sets R0/R1, sched_barrier(0) pins
//      the order). The wait before MFMA becomes the compiler's lgkmcnt(8)
//      (already satisfied) instead of a blocking lgkmcnt(0) -- removing the
//      read->use dependency that kept every prior variant (R7/R8/R9/R14) at
//      MfmaUtil ~31% (chunk = LDS burst + MFMA burst + ds-latency, SUMMED).
//      Per half-chunk: STAGE(j+2) | VMW(4)+BAR (chunk j+1 landed, all waves)
//      | FRAGS(j+1)->Rn | SB0 | MFMA(Rc) | BAR (slot-overwrite protect).
//      VM ledger invariant: entry of chunk j = {STAGE(j+1)} outstanding.
//      Keeps: both-sides XOR swizzle, setprio, XCD swizzle, R14 EPIs/grids.
// ---------------------------------------------------------------------------

typedef __bf16 bf16;
typedef bf16 bf16x8 __attribute__((ext_vector_type(8)));
typedef bf16 bf16x4 __attribute__((ext_vector_type(4)));
typedef float f32x4 __attribute__((ext_vector_type(4)));

#define BB 4
#define SS 2048
#define CC 2048
#define DD 512
#define ND3 1536          // 3*DD
#define MM 8192           // BB*SS

typedef const __attribute__((address_space(1))) unsigned int g_u32;
typedef __attribute__((address_space(3))) unsigned int l_u32;

__device__ __forceinline__ void gl_lds16(const bf16* g, bf16* l) {
    __builtin_amdgcn_global_load_lds((g_u32*)g, (l_u32*)l, 16, 0, 0);
}

#define VMW(n) asm volatile("s_waitcnt vmcnt(" #n ")" ::: "memory")
#define BAR    __builtin_amdgcn_s_barrier()
#define SB0    __builtin_amdgcn_sched_barrier(0)

// XCD-aware swizzle: dispatch slot d runs on XCD d%8; remap so XCD k gets a
// CONTIGUOUS work range. Requires nwg % 8 == 0 (grids: 768/1024/256/1024).
__device__ __forceinline__ void xcd_swz(int& bx, int& by, int& bz) {
    const int gx = gridDim.x, gy = gridDim.y;
    const int nwg = gx * gy * gridDim.z;
    const int d = (blockIdx.z * gy + blockIdx.y) * gx + blockIdx.x;
    const int s = (d & 7) * (nwg >> 3) + (d >> 3);
    bx = s % gx;
    const int t2 = s / gx;
    by = t2 % gy;
    bz = t2 / gy;
}

// ---------------- prep: fp32->bf16 for x/Wqkv/Wo + zero rsum ---------------
#define N4_X   (MM * CC / 4)          // 4194304
#define N4_WQ  (ND3 * CC / 4)         //  786432
#define N4_WO  (CC * DD / 4)          //  262144
#define N4_RS  (MM / 4)               //    2048
#define N4_TOT (N4_X + N4_WQ + N4_WO + N4_RS)

__global__ __launch_bounds__(256) void prep(const float* __restrict__ x,
                                            const float* __restrict__ Wqkv,
                                            const float* __restrict__ Wo,
                                            bf16* __restrict__ xb,
                                            bf16* __restrict__ wqkvb,
                                            bf16* __restrict__ wob,
                                            float* __restrict__ rsum) {
    int i = blockIdx.x * 256 + threadIdx.x;
    const int stride = gridDim.x * 256;
    for (; i < N4_TOT; i += stride) {
        if (i < N4_X + N4_WQ + N4_WO) {
            const float* src; bf16* dst; int j = i;
            if (j < N4_X)                { src = x;    dst = xb; }
            else if (j < N4_X + N4_WQ)   { src = Wqkv; dst = wqkvb; j -= N4_X; }
            else                         { src = Wo;   dst = wob;   j -= N4_X + N4_WQ; }
            float4 v = ((const float4*)src)[j];
            bf16x4 o;
            o[0] = (bf16)v.x; o[1] = (bf16)v.y; o[2] = (bf16)v.z; o[3] = (bf16)v.w;
            ((bf16x4*)dst)[j] = o;
        } else {
            int j = i - (N4_X + N4_WQ + N4_WO);
            ((float4*)rsum)[j] = float4{0.f, 0.f, 0.f, 0.f};
        }
    }
}

// ---------------------------------------------------------------------------
// 128x128 ring core, pipelined. 4 waves (2Mx2N), per-wave 64x64 (acc[4][4]).
// K in 32-col chunks, 3-slot static-LDS ring (48 KB -> 3 wgs/CU at ~155 reg).
// Steady half (chunk j, regs Rc hold j's frags loaded LAST half):
//   STAGE(j+2)            [overwrites slot (j-1)%3 -- safe: prev half's
//                          trailing BAR followed all-waves' lgkm of FRAGS(j-1)]
//   VMW(4); BAR           [entry outstanding {S(j+1)}+S(j+2)=8 -> waits S(j+1);
//                          barrier: slot j+1 full for ALL waves (staging is
//                          cross-wave: wave w writes rows w*16.. of each half)]
//   FRAGS(j+1) -> Rn      [8 ds_read issued, NOT waited]
//   sched_barrier(0)      [reads pinned before MFMAs; compiler auto-emits
//                          lgkmcnt(8) for Rc -- already satisfied]
//   setprio1 MFMA(Rc) setprio0
//   BAR                   [no wave stages over slot j%3 until all read it]
// Tail: VMW(0); BAR; FRAGS(NC-1); SB0; MFMA(NC-2); MFMA(NC-1).
// EPI: 0 = scale*acc + bias[col], row-major fp32 stores (k_out)
//      3 = QKV split: col<1024 row-major bf16; col>=1024 transposed into vT
//      4 = scoresT: exp(scale*acc), packed b64 C^T store, col-sum atomics
//      5 = pvT: acc/rowsum[col], packed b64 C^T store
// ---------------------------------------------------------------------------
#define SLOT3 8192        // bf16 elems per slot (A 4096 + B 4096)

template <bool OUT_BF16, int EPI>
__device__ __forceinline__ void gemm128_body(const bf16* __restrict__ A,
                                             const bf16* __restrict__ Bm,
                                             const float* __restrict__ bias,
                                             float* __restrict__ rowsum,
                                             bf16* __restrict__ vTp,
                                             void* __restrict__ Cv,
                                             int K, int lda, int ldb, int ldc,
                                             long ab, long bb, long cb,
                                             float scale) {
    __shared__ bf16 lds[3 * SLOT3];
    int bx, by, bz;
    xcd_swz(bx, by, bz);
    A  += (size_t)bz * ab;
    Bm += (size_t)bz * bb;
    const int m0 = by * 128, n0 = bx * 128;
    const int t = threadIdx.x, lane = t & 63, w = t >> 6;
    const int wm = (w >> 1) * 64, wn = (w & 1) * 64;
    const int cl = lane & 15, q = lane >> 4;
    const int swzr = (q ^ ((cl >> 1) & 3)) * 8;        // read-side XOR swizzle
    const int srow = t >> 2;                           // 0..63
    const int swz  = (t & 3) ^ ((t >> 3) & 3);
    const bf16* pa = A  + (size_t)(m0 + srow) * lda + swz * 8;
    const bf16* pb = Bm + (size_t)(n0 + srow) * ldb + swz * 8;
    bf16* lw = lds + w * 512;                          // wave-uniform base

    f32x4 acc[4][4] = {};
    const int NC = K >> 5;                             // K/32 chunks (even, >=4)

    auto STAGE = [&](int j, int sl) {                  // slot sl = j % 3
        bf16* s = lw + sl * SLOT3;
        const bf16* ga = pa + j * 32;
        const bf16* gb = pb + j * 32;
        gl_lds16(ga,                    s);
        gl_lds16(ga + (size_t)64 * lda, s + 2048);
        gl_lds16(gb,                    s + 4096);
        gl_lds16(gb + (size_t)64 * ldb, s + 4096 + 2048);
    };
    auto FRAGS = [&](int sl, bf16x8 (&af)[4], bf16x8 (&bfr)[4]) {
        const bf16* sa = lds + sl * SLOT3 + (wm + cl) * 32 + swzr;
        const bf16* sb = lds + sl * SLOT3 + 4096 + (wn + cl) * 32 + swzr;
#pragma unroll
        for (int i = 0; i < 4; i++)  af[i]  = *(const bf16x8*)(sa + i * 512);
#pragma unroll
        for (int jj = 0; jj < 4; jj++) bfr[jj] = *(const bf16x8*)(sb + jj * 512);
    };
    auto MFMAS = [&](bf16x8 (&af)[4], bf16x8 (&bfr)[4]) {
        __builtin_amdgcn_s_setprio(1);
#pragma unroll
        for (int i = 0; i < 4; i++)
#pragma unroll
            for (int jj = 0; jj < 4; jj++)
                acc[i][jj] = __builtin_amdgcn_mfma_f32_16x16x32_bf16(
                                 af[i], bfr[jj], acc[i][jj], 0, 0, 0);
        __builtin_amdgcn_s_setprio(0);
    };

    bf16x8 a0[4], b0[4], a1[4], b1[4];

    // prologue: stage chunks 0,1; wait chunk 0 (leaves {STAGE(1)} = 4 ops);
    // issue FRAGS(0) into R0.
    STAGE(0, 0); STAGE(1, 1);
    VMW(4); BAR;
    FRAGS(0, a0, b0);

    int st = 2;                        // LDS slot for next STAGE (chunk j+2)
    int fr = 1;                        // LDS slot for next FRAGS (chunk j+1)
    for (int j = 0; j < NC - 3; j += 2) {
        // ---- half A: compute chunk j (R0), load chunk j+1 (R1) ----
        STAGE(j + 2, st); st = (st == 2) ? 0 : st + 1;
        VMW(4); BAR;
        FRAGS(fr, a1, b1); fr = (fr == 2) ? 0 : fr + 1;
        SB0;
        MFMAS(a0, b0);
        BAR;
        // ---- half B: compute chunk j+1 (R1), load chunk j+2 (R0) ----
        STAGE(j + 3, st); st = (st == 2) ? 0 : st + 1;
        VMW(4); BAR;
        FRAGS(fr, a0, b0); fr = (fr == 2) ? 0 : fr + 1;
        SB0;
        MFMAS(a1, b1);
        BAR;
    }
    // tail: R0 holds chunk NC-2; {STAGE(NC-1)} outstanding.
    VMW(0); BAR;                       // chunk NC-1 landed everywhere
    FRAGS(fr, a1, b1);                 // chunk NC-1
    SB0;
    MFMAS(a0, b0);                     // chunk NC-2
    MFMAS(a1, b1);                     // chunk NC-1 (compiler waits lgkm)

    if constexpr (EPI == 4) {          // scoresT: exp, packed C^T, col-sums
        float cs[4] = {0.f, 0.f, 0.f, 0.f};
#pragma unroll
        for (int i = 0; i < 4; i++)
#pragma unroll
            for (int jj = 0; jj < 4; jj++) {
                int col = n0 + wn + jj * 16 + cl;
                int row = m0 + wm + i * 16 + q * 4;
                bf16x4 o;
#pragma unroll
                for (int r = 0; r < 4; r++) {
                    float e = __expf(acc[i][jj][r] * scale);
                    cs[jj] += e;
                    o[r] = (bf16)e;
                }
                *(bf16x4*)&((bf16*)Cv)[(size_t)bz * cb + (size_t)col * ldc + row] = o;
            }
#pragma unroll
        for (int jj = 0; jj < 4; jj++) {
            cs[jj] += __shfl_xor(cs[jj], 16, 64);
            cs[jj] += __shfl_xor(cs[jj], 32, 64);
        }
        if (q == 0) {
#pragma unroll
            for (int jj = 0; jj < 4; jj++)
                atomicAdd(&rowsum[(size_t)bz * SS + n0 + wn + jj * 16 + cl], cs[jj]);
        }
        return;
    }

    if constexpr (EPI == 5) {          // pvT: /rowsum[col=q], packed C^T
        float inv[4];
#pragma unroll
        for (int jj = 0; jj < 4; jj++)
            inv[jj] = 1.0f / rowsum[(size_t)bz * SS + n0 + wn + jj * 16 + cl];
#pragma unroll
        for (int i = 0; i < 4; i++)
#pragma unroll
            for (int jj = 0; jj < 4; jj++) {
                int col = n0 + wn + jj * 16 + cl;
                int row = m0 + wm + i * 16 + q * 4;
                bf16x4 o;
#pragma unroll
                for (int r = 0; r < 4; r++) o[r] = (bf16)(acc[i][jj][r] * inv[jj]);
                *(bf16x4*)&((bf16*)Cv)[(size_t)bz * cb + (size_t)col * ldc + row] = o;
            }
        return;
    }

    const bool v_block = (EPI == 3) && (n0 >= 1024);
#pragma unroll
    for (int i = 0; i < 4; i++) {
#pragma unroll
        for (int jj = 0; jj < 4; jj++) {
            int col = n0 + wn + jj * 16 + cl;
            float bvv = bias ? bias[col] : 0.0f;
            if (v_block) {
                int row = m0 + wm + i * 16 + q * 4;
                int b = row >> 11, s = row & 2047;
                bf16x4 o;
#pragma unroll
                for (int r = 0; r < 4; r++) o[r] = (bf16)(acc[i][jj][r] * scale + bvv);
                *(bf16x4*)&vTp[((size_t)b * DD + (col - 1024)) * SS + s] = o;
            } else {
#pragma unroll
                for (int r = 0; r < 4; r++) {
                    int row = m0 + wm + i * 16 + q * 4 + r;
                    float val = acc[i][jj][r] * scale + bvv;
                    if (OUT_BF16)
                        ((bf16*)Cv)[(size_t)bz * cb + (size_t)row * ldc + col] = (bf16)val;
                    else
                        ((float*)Cv)[(size_t)bz * cb + (size_t)row * ldc + col] = val;
                }
            }
        }
    }
}

// distinct names so rocprof reports per-role counters
__global__ __launch_bounds__(256, 2) void k_qkv(const bf16* A, const bf16* Bm,
        const float* bias, bf16* vTp, void* Cv, int K, int lda, int ldb, int ldc,
        float scale) {
    gemm128_body<true, 3>(A, Bm, bias, nullptr, vTp, Cv, K, lda, ldb, ldc, 0, 0, 0, scale);
}
__global__ __launch_bounds__(256, 2) void k_score(const bf16* A, const bf16* Bm,
        float* rowsum, void* Cv, int K, int lda, int ldb, int ldc,
        long ab, long bb, long cb, float scale) {
    gemm128_body<true, 4>(A, Bm, nullptr, rowsum, nullptr, Cv, K, lda, ldb, ldc, ab, bb, cb, scale);
}
__global__ __launch_bounds__(256, 2) void k_pv(const bf16* A, const bf16* Bm,
        float* rowsum, void* Cv, int K, int lda, int ldb, int ldc,
        long ab, long bb, long cb) {
    gemm128_body<true, 5>(A, Bm, nullptr, rowsum, nullptr, Cv, K, lda, ldb, ldc, ab, bb, cb, 1.0f);
}
__global__ __launch_bounds__(256, 2) void k_out(const bf16* A, const bf16* Bm,
        const float* bias, void* Cv, int K, int lda, int ldb, int ldc,
        float scale) {
    gemm128_body<false, 0>(A, Bm, bias, nullptr, nullptr, Cv, K, lda, ldb, ldc, 0, 0, 0, scale);
}

// ---------------------------------------------------------------------------
extern "C" void kernel_launch(void* const* d_in, const int* in_sizes, int n_in,
                              void* d_out, int out_size, void* d_ws, size_t ws_size,
                              hipStream_t stream) {
    const float* x    = (const float*)d_in[0];  // (4,2048,2048)
    const float* Wqkv = (const float*)d_in[1];  // (1536,2048)
    const float* bqkv = (const float*)d_in[2];  // (1536,)
    const float* Wo   = (const float*)d_in[3];  // (2048,512)
    const float* bo   = (const float*)d_in[4];  // (2048,)
    float* out = (float*)d_out;                 // (4,2048,2048) fp32

    char* ws = (char*)d_ws;
    size_t off = 0;
    bf16* xb    = (bf16*)(ws + off); off += (size_t)MM * CC * 2;       // 32 MB
    bf16* wqkvb = (bf16*)(ws + off); off += (size_t)ND3 * CC * 2;      // 6 MB
    bf16* wob   = (bf16*)(ws + off); off += (size_t)CC * DD * 2;       // 2 MB
    bf16* qkvb  = (bf16*)(ws + off); off += (size_t)MM * ND3 * 2;      // 24 MB
    bf16* vT    = (bf16*)(ws + off); off += (size_t)BB * DD * SS * 2;  // 8 MB
    bf16* expS  = (bf16*)(ws + off); off += (size_t)BB * SS * SS * 2;  // 32 MB
    bf16* ctxb  = (bf16*)(ws + off); off += (size_t)MM * DD * 2;       // 8 MB
    float* rsum = (float*)(ws + off); off += (size_t)MM * 4;           // 32 KB

    // 1. convert inputs to bf16 + zero rsum
    prep<<<2048, 256, 0, stream>>>(x, Wqkv, Wo, xb, wqkvb, wob, rsum);

    // 2. qkv = x Wqkv^T + bqkv; q,k -> qkvb rows, v -> vT transposed
    //    grid 12x64 = 768 wgs
    k_qkv<<<dim3(ND3 / 128, MM / 128, 1), 256, 0, stream>>>(
        xb, wqkvb, bqkv, vT, qkvb, CC, CC, CC, ND3, 1.0f);

    // 3. expS = exp(q k^T / sqrt(d)) via S^T = k q^T; packed C^T store gives
    //    expS[q][k] row-major; col-sum atomics -> rsum[q].  16x16x4 = 1024 wgs
    k_score<<<dim3(SS / 128, SS / 128, BB), 256, 0, stream>>>(
        qkvb + 512 /*k*/, qkvb /*q*/, rsum, expS,
        DD, ND3, ND3, SS,
        (long)SS * ND3, (long)SS * ND3, (long)SS * SS,
        0.044194173824159216f /* 1/sqrt(512) */);

    // 4. ctx[q][d] via ctx^T = vT expS^T; /rowsum[col]; packed C^T stores.
    //    grid 16x4x4 = 256 wgs
    k_pv<<<dim3(SS / 128, DD / 128, BB), 256, 0, stream>>>(
        vT, expS, rsum, ctxb,
        SS, SS, SS, DD,
        (long)DD * SS, (long)SS * SS, (long)SS * DD);

    // 5. out = ctx Wo^T + bo  (M=8192, N=2048, K=512) -> fp32.  16x64 = 1024
    k_out<<<dim3(CC / 128, MM / 128, 1), 256, 0, stream>>>(
        ctxb, wob, bo, out, DD, DD, DD, CC, 1.0f);

    (void)in_sizes; (void)n_in; (void)out_size; (void)ws_size;
}